// Round 3
// baseline (1067.031 us; speedup 1.0000x reference)
//
#include <hip/hip_runtime.h>

// diag-embed: out[i, j, j] = x[i, j], zeros elsewhere.
// x: [8192, 176] fp32; out: [8192, 176, 176] fp32 (~1.015 GB).
//
// Strategy: 99.4% of output bytes are zero. hipMemsetAsync runs at the
// device fill rate (measured 6.2 TB/s on this harness's own poison fills),
// so zero the whole buffer with memset, then scatter only the 1.44M
// diagonal elements with a tiny kernel. Both on `stream` (memset first —
// stream order protects the diagonal writes).

#define D_MODEL 176

__global__ __launch_bounds__(256) void diag_scatter_kernel(
    const float* __restrict__ x,
    float* __restrict__ out,
    unsigned int n) {               // n = 8192*176 = 1,441,792
    unsigned int t = blockIdx.x * 256u + threadIdx.x;
    if (t >= n) return;

    float val = x[t];               // coalesced read of the whole input
    unsigned int i = t / D_MODEL;   // batch index (magic-mul)
    unsigned int j = t - i * D_MODEL;
    // out[i][j][j] -> element index i*176*176 + j*177  (max ~253.7M < 2^31)
    out[i * (D_MODEL * D_MODEL) + j * (D_MODEL + 1)] = val;
}

extern "C" void kernel_launch(void* const* d_in, const int* in_sizes, int n_in,
                              void* d_out, int out_size, void* d_ws, size_t ws_size,
                              hipStream_t stream) {
    const float* x = (const float*)d_in[0];
    float* out = (float*)d_out;

    // Zero the full output at fill rate (~164 us for 1.015 GB @ 6.2 TB/s).
    hipMemsetAsync(d_out, 0, (size_t)out_size * sizeof(float), stream);

    unsigned int n = (unsigned int)in_sizes[0];        // 1,441,792
    unsigned int grid = (n + 255u) / 256u;             // 5,632 blocks
    diag_scatter_kernel<<<grid, 256, 0, stream>>>(x, out, n);
}

// Round 4
// 1008.288 us; speedup vs baseline: 1.0583x; 1.0583x over previous
//
#include <hip/hip_runtime.h>

// diag-embed: out[i, j, j] = x[i, j], zeros elsewhere.
// x: [8192, 176] fp32; out: [8192, 176, 176] fp32 (~1.015 GB).
//
// R4: single fused kernel, fill-style. The rocclr fill hits 6.2 TB/s with a
// grid-stride loop of plain stores; R2 (1 nt-store/thread, 248k blocks) only
// hit 3 TB/s. So: 4096 blocks x 256 threads, grid-stride over float4s,
// temporal stores, ~60 stores/thread. Diagonal value fused inline:
// out-row r = i*176 + j, and x[i*176+j] == x[r], so the load index is free.

#define D_MODEL 176
#define ROW_VEC (D_MODEL / 4)   // 44 float4 per output row

typedef float fvec4 __attribute__((ext_vector_type(4)));

__global__ __launch_bounds__(256) void diag_embed_kernel(
    const float* __restrict__ x,
    fvec4* __restrict__ out,
    unsigned int total_vec) {
    unsigned int stride = gridDim.x * 256u;
    for (unsigned int idx = blockIdx.x * 256u + threadIdx.x;
         idx < total_vec; idx += stride) {
        unsigned int row = idx / ROW_VEC;          // magic-mul div
        unsigned int pos = idx - row * ROW_VEC;    // 0..43
        unsigned int j   = row % D_MODEL;          // diagonal col (magic-mul)

        fvec4 v = (fvec4)(0.f, 0.f, 0.f, 0.f);
        unsigned int off = j - pos * 4u;           // in-window iff < 4 (unsigned)
        if (off < 4u) {
            v[off] = x[row];                       // x[i*176+j] == x[row]
        }
        out[idx] = v;                              // plain temporal store
    }
}

extern "C" void kernel_launch(void* const* d_in, const int* in_sizes, int n_in,
                              void* d_out, int out_size, void* d_ws, size_t ws_size,
                              hipStream_t stream) {
    const float* x = (const float*)d_in[0];
    fvec4* out = (fvec4*)d_out;

    unsigned int total_vec = (unsigned int)(out_size / 4);  // 63,438,848
    // 4096 blocks = 16 blocks/CU; each thread ~60 iterations.
    diag_embed_kernel<<<4096, 256, 0, stream>>>(x, out, total_vec);
}

// Round 5
// 989.024 us; speedup vs baseline: 1.0789x; 1.0195x over previous
//
#include <hip/hip_runtime.h>

// diag-embed: out[i, j, j] = x[i, j], zeros elsewhere.
// x: [8192, 176] fp32; out: [8192, 176, 176] fp32 (~1.015 GB).
//
// R5 = revert to R2 structure (measured best: kernel ~171 us = 5.9 TB/s,
// at the device fill-rate ceiling). One 16B nt store per thread.
// Timing model: dur_us = ws-poison (654) + out-poison (165) + kernel.
// Kernel floor = 1.015 GB / 6.25 TB/s = ~163 us -> we are within ~5%.

#define D_MODEL 176
#define ROW_VEC (D_MODEL / 4)   // 44 float4 per output row

typedef float fvec4 __attribute__((ext_vector_type(4)));

__global__ __launch_bounds__(256) void diag_embed_kernel(
    const float* __restrict__ x,
    fvec4* __restrict__ out,
    unsigned int total_vec) {
    unsigned int idx = blockIdx.x * 256u + threadIdx.x;
    if (idx >= total_vec) return;

    unsigned int row = idx / ROW_VEC;             // output row (magic-mul div)
    unsigned int pos = idx - row * ROW_VEC;       // float4 pos in row, 0..43
    unsigned int j   = row % D_MODEL;             // diagonal column

    fvec4 v = (fvec4)(0.f, 0.f, 0.f, 0.f);
    unsigned int off = j - pos * 4u;              // in-window iff < 4 (unsigned)
    if (off < 4u) {
        v[off] = x[row];                          // x[i*176 + j] == x[row]
    }
    __builtin_nontemporal_store(v, &out[idx]);
}

extern "C" void kernel_launch(void* const* d_in, const int* in_sizes, int n_in,
                              void* d_out, int out_size, void* d_ws, size_t ws_size,
                              hipStream_t stream) {
    const float* x = (const float*)d_in[0];
    fvec4* out = (fvec4*)d_out;

    unsigned int total_vec = (unsigned int)(out_size / 4);  // 63,438,848
    unsigned int grid = (total_vec + 255u) / 256u;          // 247,808 blocks

    diag_embed_kernel<<<grid, 256, 0, stream>>>(x, out, total_vec);
}